// Round 3
// baseline (115.233 us; speedup 1.0000x reference)
//
#include <hip/hip_runtime.h>
#include <math.h>

#define NB 64
#define NP 8732
#define NC 81
#define NROWS (NB * NP)          // 558848
#define RPB 64                   // rows per tile
#define TPB 256
#define NTILES (NROWS / RPB)     // 8732 exactly
#define GRID 768                 // 3 blocks/CU * 256 CU
#define TILE_FLOATS (RPB * NC)   // 5184
#define TILE_F4 (TILE_FLOATS / 4)// 1296
#define PF_N 6                   // ceil(1296/256); i=5 valid only for tid<16
#define KPT 35                   // ceil(8732/256); i=34 valid only for tid<28

// ws layout:
//   acc      : double[8]       @ 0     (acc[0] = top-K negative CE sum)
//   partials : double[GRID*3]  @ 64    (ce_pos, sl1, num_pos per block)
//   bg       : float[NROWS]    @ 64 + GRID*24
#define PART_OFF 64
#define BG_OFF   (64 + GRID * 3 * 8)

__global__ __launch_bounds__(TPB) void mb_rows(
    const float* __restrict__ conf,
    const float* __restrict__ pred,
    const float* __restrict__ gt,
    const int*   __restrict__ labels,
    float* __restrict__ bg,
    double* __restrict__ partials,
    double* __restrict__ acc)
{
    __shared__ float buf[2][TILE_FLOATS];   // 41472 B double buffer
    __shared__ double s_red[4][3];

    const int tid = threadIdx.x;
    if (blockIdx.x == 0 && tid == 0) acc[0] = 0.0;  // select runs after us

    const int r   = tid >> 2;               // 0..63 : row within tile
    const int h   = tid & 3;                // quarter-row id
    const int off = (h == 0) ? 0 : h * 20 + 1;  // {0,21,41,61}

    double ce = 0.0, sl = 0.0, npd = 0.0;

    int t = blockIdx.x;
    // ---- prologue: stage tile t into buf[0] ----
    {
        const float4* src = (const float4*)(conf + (size_t)t * TILE_FLOATS);
        float4* dst = (float4*)buf[0];
        #pragma unroll
        for (int i = 0; i < PF_N; ++i) {
            const int idx = i * TPB + tid;
            if (i < 5 || tid < 16) dst[idx] = src[idx];
        }
    }
    __syncthreads();

    int p = 0;
    for (; t < NTILES; t += GRID) {
        const int tn = t + GRID;
        const bool hn = (tn < NTILES);
        float4 pf[PF_N];
        if (hn) {   // issue next-tile loads EARLY; they fly under compute
            const float4* src = (const float4*)(conf + (size_t)tn * TILE_FLOATS);
            #pragma unroll
            for (int i = 0; i < PF_N; ++i) {
                const int idx = i * TPB + tid;
                if (i < 5 || tid < 16) pf[i] = src[idx];
            }
        }

        // ---- compute tile t from buf[p]; row values cached in VGPRs ----
        const float* rp = buf[p] + r * NC;
        float v[21];
        #pragma unroll
        for (int j = 0; j < 20; ++j) v[j] = rp[off + j];
        v[20] = (h == 0) ? rp[20] : -__builtin_inff();

        float m = v[0];
        #pragma unroll
        for (int j = 1; j < 21; ++j) m = fmaxf(m, v[j]);
        m = fmaxf(m, __shfl_xor(m, 1));
        m = fmaxf(m, __shfl_xor(m, 2));

        float s = 0.0f;
        #pragma unroll
        for (int j = 0; j < 21; ++j) s += __expf(v[j] - m);  // exp(-inf)=0
        s += __shfl_xor(s, 1);
        s += __shfl_xor(s, 2);

        const float lse = m + __logf(s);

        if (h == 0) {
            const int row = t * RPB + r;
            bg[row] = lse - v[0];                    // -log_softmax[...,0]
            const int lbl = labels[row];
            if (lbl > 0) {
                ce  += (double)(lse - rp[lbl]);
                npd += 1.0;
                float4 pv = ((const float4*)pred)[row];
                float4 gv = ((const float4*)gt)[row];
                float d;
                d = fabsf(pv.x - gv.x); sl += (d < 1.f) ? 0.5f * d * d : d - 0.5f;
                d = fabsf(pv.y - gv.y); sl += (d < 1.f) ? 0.5f * d * d : d - 0.5f;
                d = fabsf(pv.z - gv.z); sl += (d < 1.f) ? 0.5f * d * d : d - 0.5f;
                d = fabsf(pv.w - gv.w); sl += (d < 1.f) ? 0.5f * d * d : d - 0.5f;
            }
        }

        __syncthreads();                 // everyone done reading buf[p^1] (iter t-1)
        if (hn) {                        // drain pf (vmcnt auto) and fill other buffer
            float4* dst = (float4*)buf[p ^ 1];
            #pragma unroll
            for (int i = 0; i < PF_N; ++i) {
                const int idx = i * TPB + tid;
                if (i < 5 || tid < 16) dst[idx] = pf[i];
            }
        }
        __syncthreads();
        p ^= 1;
    }

    // ---- block reduce (once, after all tiles) ----
    #pragma unroll
    for (int o = 32; o; o >>= 1) {
        ce  += __shfl_xor(ce, o);
        sl  += __shfl_xor(sl, o);
        npd += __shfl_xor(npd, o);
    }
    const int wid = tid >> 6, lane = tid & 63;
    if (lane == 0) { s_red[wid][0] = ce; s_red[wid][1] = sl; s_red[wid][2] = npd; }
    __syncthreads();
    if (tid == 0) {
        double a = 0, b = 0, c = 0;
        for (int w = 0; w < 4; ++w) { a += s_red[w][0]; b += s_red[w][1]; c += s_red[w][2]; }
        partials[blockIdx.x * 3 + 0] = a;
        partials[blockIdx.x * 3 + 1] = b;
        partials[blockIdx.x * 3 + 2] = c;
    }
}

// One 256-thread block per batch row. Keys cached in registers; exact K-th
// largest via 32-step binary search (1 barrier/iter, iteration-indexed cnt).
__global__ __launch_bounds__(256) void mb_select(
    const float* __restrict__ bg,
    const int*   __restrict__ labels,
    double* __restrict__ acc)
{
    __shared__ unsigned cnt[33];
    __shared__ unsigned s_np[4];
    __shared__ double   s_sum[4];
    __shared__ unsigned s_cgt[4];

    const int b = blockIdx.x, tid = threadIdx.x;
    const int lane = tid & 63, wid = tid >> 6;

    unsigned k[KPT];
    unsigned np = 0;
    #pragma unroll
    for (int i = 0; i < KPT; ++i) {
        unsigned key = 0u;
        if (i < 34 || tid < 28) {
            const int idx = i * 256 + tid;
            const int   lbl = labels[b * NP + idx];
            const float vv  = bg[b * NP + idx];
            // negatives: bits+1 (order-preserving, bg>=0); positives: 0
            key = (lbl > 0) ? 0u : (__float_as_uint(vv) + 1u);
            np += (lbl > 0) ? 1u : 0u;
        }
        k[i] = key;
    }
    for (int i = tid; i < 33; i += 256) cnt[i] = 0u;

    #pragma unroll
    for (int o = 32; o; o >>= 1) np += __shfl_xor(np, o);
    if (lane == 0) s_np[wid] = np;
    __syncthreads();

    const unsigned npos = s_np[0] + s_np[1] + s_np[2] + s_np[3];
    unsigned K = 3u * npos;
    const unsigned nneg = NP - npos;
    if (K > nneg) K = nneg;
    if (K == 0) return;

    // smallest x with count(key > x) < K  ->  x = K-th largest key
    unsigned lo = 0u, hi = 0xFFFFFFFFu;
    for (int it = 0; it < 32 && lo < hi; ++it) {
        const unsigned mid = lo + ((hi - lo) >> 1);
        unsigned c = 0;
        #pragma unroll
        for (int i = 0; i < KPT; ++i) c += (k[i] > mid) ? 1u : 0u;
        #pragma unroll
        for (int o = 32; o; o >>= 1) c += __shfl_xor(c, o);
        if (lane == 0) atomicAdd(&cnt[it], c);
        __syncthreads();
        if (cnt[it] < K) hi = mid; else lo = mid + 1;
    }
    const unsigned V = lo;   // exact key of K-th largest, >= 1

    double ssum = 0.0; unsigned cgt = 0;
    #pragma unroll
    for (int i = 0; i < KPT; ++i) {
        const unsigned kk = k[i];
        if (kk > V) { ssum += (double)__uint_as_float(kk - 1u); cgt++; }
    }
    #pragma unroll
    for (int o = 32; o; o >>= 1) { ssum += __shfl_xor(ssum, o); cgt += __shfl_xor(cgt, o); }
    if (lane == 0) { s_sum[wid] = ssum; s_cgt[wid] = cgt; }
    __syncthreads();
    if (tid == 0) {
        double tot = s_sum[0] + s_sum[1] + s_sum[2] + s_sum[3];
        const unsigned cg = s_cgt[0] + s_cgt[1] + s_cgt[2] + s_cgt[3];
        tot += (double)(K - cg) * (double)__uint_as_float(V - 1u);  // ties at V
        atomicAdd(&acc[0], tot);
    }
}

__global__ __launch_bounds__(256) void mb_final(
    const double* __restrict__ acc,
    const double* __restrict__ partials,
    float* __restrict__ out)
{
    __shared__ double s_r[4][3];
    const int tid = threadIdx.x;
    double ce = 0, sl = 0, np = 0;
    for (int i = tid; i < GRID; i += 256) {
        ce += partials[3 * i + 0];
        sl += partials[3 * i + 1];
        np += partials[3 * i + 2];
    }
    #pragma unroll
    for (int o = 32; o; o >>= 1) {
        ce += __shfl_xor(ce, o);
        sl += __shfl_xor(sl, o);
        np += __shfl_xor(np, o);
    }
    const int wid = tid >> 6, lane = tid & 63;
    if (lane == 0) { s_r[wid][0] = ce; s_r[wid][1] = sl; s_r[wid][2] = np; }
    __syncthreads();
    if (tid == 0) {
        double a = 0, b = 0, c = 0;
        for (int w = 0; w < 4; ++w) { a += s_r[w][0]; b += s_r[w][1]; c += s_r[w][2]; }
        const double cls = a + acc[0];
        const float npf = (float)c;
        out[0] = (float)b   / npf;   // smooth_l1_loss / num_pos
        out[1] = (float)cls / npf;   // classification_loss / num_pos
    }
}

extern "C" void kernel_launch(void* const* d_in, const int* in_sizes, int n_in,
                              void* d_out, int out_size, void* d_ws, size_t ws_size,
                              hipStream_t stream)
{
    const float* conf   = (const float*)d_in[0];
    const float* pred   = (const float*)d_in[1];
    const int*   labels = (const int*)d_in[2];
    const float* gt     = (const float*)d_in[3];
    float* out = (float*)d_out;

    double* acc      = (double*)d_ws;
    double* partials = (double*)((char*)d_ws + PART_OFF);
    float*  bg       = (float*)((char*)d_ws + BG_OFF);

    mb_rows<<<GRID, TPB, 0, stream>>>(conf, pred, gt, labels, bg, partials, acc);
    mb_select<<<NB, 256, 0, stream>>>(bg, labels, acc);
    mb_final<<<1, 256, 0, stream>>>(acc, partials, out);
}

// Round 4
// 73.968 us; speedup vs baseline: 1.5579x; 1.5579x over previous
//
#include <hip/hip_runtime.h>
#include <math.h>

#define NB 64
#define NP 8732
#define NC 81
#define NROWS (NB * NP)            // 558848
#define RPB 64                     // rows per tile/block
#define TPB 256
#define NTILES (NROWS / RPB)       // 8732 (exact)
#define TILE_FLOATS (RPB * NC)     // 5184
#define TILE_F4 (TILE_FLOATS / 4)  // 1296 = 5*256 + 16
#define KPT 35                     // ceil(NP/256); i=34 valid only for tid<28

// ws layout:
//   acc      : double[8]          @ 0    acc[0]=topK_neg, acc[1]=ce_pos, acc[2]=sl1, acc[3]=num_pos
//   partials : double[NTILES*3]   @ 64
//   bg       : float[NROWS]       @ BG_OFF
#define PART_OFF 64
#define BG_OFF (PART_OFF + NTILES * 3 * 8)   // 209632 (16B aligned)

__global__ __launch_bounds__(TPB) void mb_rows(
    const float* __restrict__ conf,
    const float* __restrict__ pred,
    const float* __restrict__ gt,
    const int*   __restrict__ labels,
    float* __restrict__ bg,
    double* __restrict__ partials,
    double* __restrict__ acc)
{
    __shared__ __align__(16) float tile[TILE_FLOATS];   // 20736 B -> 7 blocks/CU
    __shared__ double s_red[4][3];

    const int tid = threadIdx.x;
    const int t   = blockIdx.x;

    if (t == 0 && tid == 0) { acc[0] = 0.0; acc[1] = 0.0; acc[2] = 0.0; acc[3] = 0.0; }

    // ---- async stage: 1296 float4 = 20736 B, linear lane order ----
    const float4* src4  = (const float4*)(conf + (size_t)t * TILE_FLOATS);
    float4*       tile4 = (float4*)tile;
    #pragma unroll
    for (int i = 0; i < 5; ++i) {
        const int idx = i * TPB + tid;
#if __has_builtin(__builtin_amdgcn_global_load_lds)
        __builtin_amdgcn_global_load_lds(
            (const __attribute__((address_space(1))) void*)(src4 + idx),
            (__attribute__((address_space(3))) void*)(tile4 + idx),
            16, 0, 0);
#else
        tile4[idx] = src4[idx];
#endif
    }
    if (tid < TILE_F4 - 5 * TPB)                   // 16-float4 tail, plain copy
        tile4[5 * TPB + tid] = src4[5 * TPB + tid];
    __syncthreads();                               // drains vmcnt+lgkmcnt

    // ---- quarter-row per thread: lanes (4r..4r+3) own row r ----
    const int r   = tid >> 2;
    const int h   = tid & 3;
    const int off = (h == 0) ? 0 : h * 20 + 1;     // {0,21,41,61}
    const float* rp = tile + r * NC;

    float v[21];
    #pragma unroll
    for (int j = 0; j < 20; ++j) v[j] = rp[off + j];
    v[20] = (h == 0) ? rp[20] : -__builtin_inff();

    float m = v[0];
    #pragma unroll
    for (int j = 1; j < 21; ++j) m = fmaxf(m, v[j]);
    m = fmaxf(m, __shfl_xor(m, 1));
    m = fmaxf(m, __shfl_xor(m, 2));

    float s = 0.0f;
    #pragma unroll
    for (int j = 0; j < 21; ++j) s += __expf(v[j] - m);   // exp(-inf)=0
    s += __shfl_xor(s, 1);
    s += __shfl_xor(s, 2);

    const float lse = m + __logf(s);

    double ce = 0.0, sl = 0.0, npd = 0.0;
    if (h == 0) {
        const int row = t * RPB + r;
        bg[row] = lse - v[0];                      // -log_softmax[...,0]
        const int lbl = labels[row];
        if (lbl > 0) {
            ce  = (double)(lse - rp[lbl]);
            npd = 1.0;
            float4 pv = ((const float4*)pred)[row];
            float4 gv = ((const float4*)gt)[row];
            float d;
            d = fabsf(pv.x - gv.x); sl += (d < 1.f) ? 0.5f * d * d : d - 0.5f;
            d = fabsf(pv.y - gv.y); sl += (d < 1.f) ? 0.5f * d * d : d - 0.5f;
            d = fabsf(pv.z - gv.z); sl += (d < 1.f) ? 0.5f * d * d : d - 0.5f;
            d = fabsf(pv.w - gv.w); sl += (d < 1.f) ? 0.5f * d * d : d - 0.5f;
        }
    }

    #pragma unroll
    for (int o = 32; o; o >>= 1) {
        ce  += __shfl_xor(ce, o);
        sl  += __shfl_xor(sl, o);
        npd += __shfl_xor(npd, o);
    }
    const int wid = tid >> 6, lane = tid & 63;
    if (lane == 0) { s_red[wid][0] = ce; s_red[wid][1] = sl; s_red[wid][2] = npd; }
    __syncthreads();
    if (tid == 0) {
        double a = 0, b = 0, c = 0;
        for (int w = 0; w < 4; ++w) { a += s_red[w][0]; b += s_red[w][1]; c += s_red[w][2]; }
        partials[t * 3 + 0] = a;
        partials[t * 3 + 1] = b;
        partials[t * 3 + 2] = c;
    }
}

// One 256-thread block per batch row: (a) reduce a stripe of partials into
// acc[1..3]; (b) exact top-K sum of bg among negatives via register-cached
// binary search over [min_neg_key, max_neg_key].
__global__ __launch_bounds__(256) void mb_select(
    const float* __restrict__ bg,
    const int*   __restrict__ labels,
    const double* __restrict__ partials,
    double* __restrict__ acc)
{
    __shared__ unsigned cnt[32];
    __shared__ unsigned s_u[4][3];     // np / maxk / mink per wave
    __shared__ double   s_d[4][3];
    __shared__ unsigned s_K, s_lo, s_hi;

    const int b = blockIdx.x, tid = threadIdx.x;
    const int lane = tid & 63, wid = tid >> 6;

    // ---- (a) stripe-reduce partials: indices j = b + 64*tid ----
    {
        double pce = 0, psl = 0, pnp = 0;
        const int j = b + (tid << 6);
        if (tid < 137 && j < NTILES) {
            pce = partials[3 * j + 0];
            psl = partials[3 * j + 1];
            pnp = partials[3 * j + 2];
        }
        #pragma unroll
        for (int o = 32; o; o >>= 1) {
            pce += __shfl_xor(pce, o);
            psl += __shfl_xor(psl, o);
            pnp += __shfl_xor(pnp, o);
        }
        if (lane == 0) { s_d[wid][0] = pce; s_d[wid][1] = psl; s_d[wid][2] = pnp; }
    }

    // ---- (b) load keys into registers ----
    unsigned k[KPT];
    unsigned np = 0, maxk = 0u, mink = 0xFFFFFFFFu;
    #pragma unroll
    for (int i = 0; i < KPT; ++i) {
        unsigned key = 0u;
        if (i < 34 || tid < 28) {
            const int idx = i * 256 + tid;
            const int   lbl = labels[b * NP + idx];
            const float vv  = bg[b * NP + idx];
            // negatives: bits+1 (order-preserving, bg>=0); positives: 0
            key = (lbl > 0) ? 0u : (__float_as_uint(vv) + 1u);
            np += (lbl > 0) ? 1u : 0u;
            if (key) { maxk = max(maxk, key); mink = min(mink, key); }
        }
        k[i] = key;
    }
    for (int i = tid; i < 32; i += 256) cnt[i] = 0u;

    #pragma unroll
    for (int o = 32; o; o >>= 1) {
        np   += __shfl_xor(np, o);
        maxk  = max(maxk, __shfl_xor(maxk, o));
        mink  = min(mink, __shfl_xor(mink, o));
    }
    if (lane == 0) { s_u[wid][0] = np; s_u[wid][1] = maxk; s_u[wid][2] = mink; }
    __syncthreads();

    if (tid == 0) {
        // finish the partials reduction -> global acc
        double pce = 0, psl = 0, pnp = 0;
        unsigned npt = 0; unsigned mx = 0, mn = 0xFFFFFFFFu;
        for (int w = 0; w < 4; ++w) {
            pce += s_d[w][0]; psl += s_d[w][1]; pnp += s_d[w][2];
            npt += s_u[w][0];
            mx = max(mx, s_u[w][1]); mn = min(mn, s_u[w][2]);
        }
        atomicAdd(&acc[1], pce);
        atomicAdd(&acc[2], psl);
        atomicAdd(&acc[3], pnp);
        unsigned K = 3u * npt;
        const unsigned nneg = NP - npt;
        if (K > nneg) K = nneg;
        s_K = K; s_lo = mn; s_hi = mx;
    }
    __syncthreads();

    const unsigned K = s_K;
    if (K == 0) return;

    // smallest x with count(key > x) < K  ->  x = key of K-th largest
    unsigned lo = s_lo, hi = s_hi;
    int it = 0;
    while (lo < hi) {
        const unsigned mid = lo + ((hi - lo) >> 1);
        unsigned c = 0;
        #pragma unroll
        for (int i = 0; i < KPT; ++i) c += (k[i] > mid) ? 1u : 0u;
        #pragma unroll
        for (int o = 32; o; o >>= 1) c += __shfl_xor(c, o);
        if (lane == 0) atomicAdd(&cnt[it], c);
        __syncthreads();
        if (cnt[it] < K) hi = mid; else lo = mid + 1;
        ++it;
    }
    const unsigned V = lo;                // exact key of K-th largest, >= 1

    double ssum = 0.0; unsigned cgt = 0;
    #pragma unroll
    for (int i = 0; i < KPT; ++i) {
        const unsigned kk = k[i];
        if (kk > V) { ssum += (double)__uint_as_float(kk - 1u); cgt++; }
    }
    #pragma unroll
    for (int o = 32; o; o >>= 1) { ssum += __shfl_xor(ssum, o); cgt += __shfl_xor(cgt, o); }
    if (lane == 0) { s_d[wid][0] = ssum; s_u[wid][0] = cgt; }
    __syncthreads();
    if (tid == 0) {
        double tot = s_d[0][0] + s_d[1][0] + s_d[2][0] + s_d[3][0];
        const unsigned cg = s_u[0][0] + s_u[1][0] + s_u[2][0] + s_u[3][0];
        tot += (double)(K - cg) * (double)__uint_as_float(V - 1u);   // ties at V
        atomicAdd(&acc[0], tot);
    }
}

__global__ __launch_bounds__(64) void mb_final(
    const double* __restrict__ acc,
    float* __restrict__ out)
{
    if (threadIdx.x == 0) {
        const double npd = acc[3];
        out[0] = (float)(acc[2] / npd);              // smooth_l1 / num_pos
        out[1] = (float)((acc[1] + acc[0]) / npd);   // classification / num_pos
    }
}

extern "C" void kernel_launch(void* const* d_in, const int* in_sizes, int n_in,
                              void* d_out, int out_size, void* d_ws, size_t ws_size,
                              hipStream_t stream)
{
    const float* conf   = (const float*)d_in[0];
    const float* pred   = (const float*)d_in[1];
    const int*   labels = (const int*)d_in[2];
    const float* gt     = (const float*)d_in[3];
    float* out = (float*)d_out;

    double* acc      = (double*)d_ws;
    double* partials = (double*)((char*)d_ws + PART_OFF);
    float*  bg       = (float*)((char*)d_ws + BG_OFF);

    mb_rows<<<NTILES, TPB, 0, stream>>>(conf, pred, gt, labels, bg, partials, acc);
    mb_select<<<NB, 256, 0, stream>>>(bg, labels, partials, acc);
    mb_final<<<1, 64, 0, stream>>>(acc, out);
}